// Round 1
// baseline (536.853 us; speedup 1.0000x reference)
//
#include <hip/hip_runtime.h>

typedef unsigned short u16;
typedef u16 u16x8 __attribute__((ext_vector_type(8)));
typedef __bf16 bf16x8 __attribute__((ext_vector_type(8)));
typedef float f32x4 __attribute__((ext_vector_type(4)));

#define C_DIM 2048
#define H_DIM 1024
#define HS_DIM 2048
#define T_DIM 512
#define NE 8

// ---- helpers ----
__device__ __forceinline__ u16 f2bf(float f) {
  unsigned u = __builtin_bit_cast(unsigned, f);
  u = (u + 0x7FFFu + ((u >> 16) & 1u)) >> 16;  // RNE
  return (u16)u;
}
__device__ __forceinline__ unsigned pk2(float a, float b) {
  return (unsigned)f2bf(a) | ((unsigned)f2bf(b) << 16);
}
__device__ __forceinline__ bf16x8 ldfrag(const u16* p) {
  union { u16x8 u; bf16x8 b; } x;
  x.u = *(const u16x8*)p;
  return x.b;
}

// ---- routing: scores, top-2 softmax, per-expert gather lists, sgate ----
__global__ __launch_bounds__(64) void routing_kernel(
    const float* __restrict__ x, const float* __restrict__ gw,
    const float* __restrict__ segw, int* __restrict__ counts,
    int* __restrict__ ptok, float* __restrict__ pw, float* __restrict__ sgate) {
  int t = blockIdx.x;
  int lane = threadIdx.x;
  const float* xr = x + (size_t)t * C_DIM;
  float s[NE];
#pragma unroll
  for (int e = 0; e < NE; e++) s[e] = 0.f;
  float sg = 0.f;
  for (int c = lane; c < C_DIM; c += 64) {
    float xv = xr[c];
#pragma unroll
    for (int e = 0; e < NE; e++) s[e] += xv * gw[e * C_DIM + c];
    sg += xv * segw[c];
  }
#pragma unroll
  for (int off = 32; off > 0; off >>= 1) {
#pragma unroll
    for (int e = 0; e < NE; e++) s[e] += __shfl_down(s[e], off);
    sg += __shfl_down(sg, off);
  }
  if (lane == 0) {
    int i0 = 0;
#pragma unroll
    for (int e = 1; e < NE; e++) if (s[e] > s[i0]) i0 = e;
    int i1 = (i0 == 0) ? 1 : 0;
#pragma unroll
    for (int e = 0; e < NE; e++) if (e != i0 && s[e] > s[i1]) i1 = e;
    float r = __expf(s[i1] - s[i0]);          // <= 1
    float w0 = 1.f / (1.f + r);
    float w1 = 1.f - w0;
    int s0 = atomicAdd(&counts[i0], 1);
    ptok[(i0 << 9) + s0] = t; pw[(i0 << 9) + s0] = w0;
    int s1 = atomicAdd(&counts[i1], 1);
    ptok[(i1 << 9) + s1] = t; pw[(i1 << 9) + s1] = w1;
    sgate[t] = 1.f / (1.f + __expf(-sg));
  }
}

// ---- fused gate+up SwiGLU GEMM: out(bf16) = silu(X Wg^T) * (X Wu^T) ----
// Tile 64x64, BK=32, 256 threads (4 waves, each a 32x32 quadrant).
// ptok==nullptr => shared-expert mode (identity gather, cnt=M).
__global__ __launch_bounds__(256) void gateup_kernel(
    const float* __restrict__ x, const float* __restrict__ Wg,
    const float* __restrict__ Wu, u16* __restrict__ outb,
    const int* __restrict__ ptok, const int* __restrict__ counts,
    int N, int K, int tiles_m, int M) {
  __shared__ u16 As[64 * 40];
  __shared__ u16 Bgs[64 * 40];
  __shared__ u16 Bus[64 * 40];

  int e, mt, cnt;
  const int* gth = nullptr;
  if (ptok) {
    e = blockIdx.y / tiles_m;
    mt = blockIdx.y - e * tiles_m;
    cnt = counts[e];
    if (mt * 64 >= cnt) return;
    gth = ptok + (e << 9);
  } else { e = 0; mt = blockIdx.y; cnt = M; }

  int nt = blockIdx.x;
  int tid = threadIdx.x;
  int r = tid >> 2, c4 = tid & 3;

  int grow = mt * 64 + r;
  int tok = gth ? ((grow < cnt) ? gth[grow] : 0) : grow;
  const float* ap = x + (size_t)tok * K;
  const float* gp = Wg + ((size_t)e * N + nt * 64 + r) * K;
  const float* up = Wu + ((size_t)e * N + nt * 64 + r) * K;

  int wave = tid >> 6, lane = tid & 63;
  int quad = lane >> 4, l16 = lane & 15;
  int mq = wave & 1, nq = wave >> 1;

  f32x4 accg[2][2] = {};
  f32x4 accu[2][2] = {};
  int a_off = (mq * 32 + l16) * 40 + quad * 8;
  int b_off = (nq * 32 + l16) * 40 + quad * 8;
  int wr0 = r * 40 + (c4 << 2);

  for (int k0 = 0; k0 < K; k0 += 32) {
    float4 a0 = *(const float4*)(ap + k0 + (c4 << 2));
    float4 a1 = *(const float4*)(ap + k0 + 16 + (c4 << 2));
    float4 g0 = *(const float4*)(gp + k0 + (c4 << 2));
    float4 g1 = *(const float4*)(gp + k0 + 16 + (c4 << 2));
    float4 u0 = *(const float4*)(up + k0 + (c4 << 2));
    float4 u1 = *(const float4*)(up + k0 + 16 + (c4 << 2));
    __syncthreads();
    *(uint2*)&As[wr0]       = make_uint2(pk2(a0.x, a0.y), pk2(a0.z, a0.w));
    *(uint2*)&As[wr0 + 16]  = make_uint2(pk2(a1.x, a1.y), pk2(a1.z, a1.w));
    *(uint2*)&Bgs[wr0]      = make_uint2(pk2(g0.x, g0.y), pk2(g0.z, g0.w));
    *(uint2*)&Bgs[wr0 + 16] = make_uint2(pk2(g1.x, g1.y), pk2(g1.z, g1.w));
    *(uint2*)&Bus[wr0]      = make_uint2(pk2(u0.x, u0.y), pk2(u0.z, u0.w));
    *(uint2*)&Bus[wr0 + 16] = make_uint2(pk2(u1.x, u1.y), pk2(u1.z, u1.w));
    __syncthreads();
    bf16x8 af0 = ldfrag(&As[a_off]);
    bf16x8 af1 = ldfrag(&As[a_off + 640]);
    bf16x8 bg0 = ldfrag(&Bgs[b_off]);
    bf16x8 bg1 = ldfrag(&Bgs[b_off + 640]);
    bf16x8 bu0 = ldfrag(&Bus[b_off]);
    bf16x8 bu1 = ldfrag(&Bus[b_off + 640]);
    accg[0][0] = __builtin_amdgcn_mfma_f32_16x16x32_bf16(af0, bg0, accg[0][0], 0, 0, 0);
    accg[0][1] = __builtin_amdgcn_mfma_f32_16x16x32_bf16(af0, bg1, accg[0][1], 0, 0, 0);
    accg[1][0] = __builtin_amdgcn_mfma_f32_16x16x32_bf16(af1, bg0, accg[1][0], 0, 0, 0);
    accg[1][1] = __builtin_amdgcn_mfma_f32_16x16x32_bf16(af1, bg1, accg[1][1], 0, 0, 0);
    accu[0][0] = __builtin_amdgcn_mfma_f32_16x16x32_bf16(af0, bu0, accu[0][0], 0, 0, 0);
    accu[0][1] = __builtin_amdgcn_mfma_f32_16x16x32_bf16(af0, bu1, accu[0][1], 0, 0, 0);
    accu[1][0] = __builtin_amdgcn_mfma_f32_16x16x32_bf16(af1, bu0, accu[1][0], 0, 0, 0);
    accu[1][1] = __builtin_amdgcn_mfma_f32_16x16x32_bf16(af1, bu1, accu[1][1], 0, 0, 0);
  }

  u16* ob = outb + (size_t)e * 512 * N;
#pragma unroll
  for (int i = 0; i < 2; i++)
#pragma unroll
    for (int j = 0; j < 2; j++)
#pragma unroll
      for (int g = 0; g < 4; g++) {
        int ml = mq * 32 + i * 16 + quad * 4 + g;
        int row = mt * 64 + ml;
        if (row < cnt) {
          float gv = accg[i][j][g], uv = accu[i][j][g];
          float sv = gv / (1.f + __expf(-gv));
          ob[(size_t)row * N + nt * 64 + nq * 32 + j * 16 + l16] = f2bf(sv * uv);
        }
      }
}

// ---- down-proj GEMM: out = (hbuf Wd^T), epilogue scale + (atomic)store ----
// ptok==nullptr => shared mode: out[row] = sgate[row]*v (plain store).
// else          => expert mode: atomicAdd(out[tok], pw*v).
__global__ __launch_bounds__(256) void down_kernel(
    const u16* __restrict__ Ab, const float* __restrict__ Wd,
    float* __restrict__ out, const int* __restrict__ ptok,
    const float* __restrict__ pw, const float* __restrict__ sgate,
    const int* __restrict__ counts, int N, int K, int tiles_m, int M) {
  __shared__ u16 As[64 * 40];
  __shared__ u16 Bs[64 * 40];

  int e, mt, cnt;
  if (ptok) {
    e = blockIdx.y / tiles_m;
    mt = blockIdx.y - e * tiles_m;
    cnt = counts[e];
    if (mt * 64 >= cnt) return;
  } else { e = 0; mt = blockIdx.y; cnt = M; }

  int nt = blockIdx.x;
  int tid = threadIdx.x;
  int r = tid >> 2, c4 = tid & 3;

  const u16* arp = Ab + ((size_t)e * 512 + mt * 64 + r) * K;
  const float* brp = Wd + ((size_t)e * N + nt * 64 + r) * K;

  int wave = tid >> 6, lane = tid & 63;
  int quad = lane >> 4, l16 = lane & 15;
  int mq = wave & 1, nq = wave >> 1;

  f32x4 acc[2][2] = {};
  int a_off = (mq * 32 + l16) * 40 + quad * 8;
  int b_off = (nq * 32 + l16) * 40 + quad * 8;
  int wrA = r * 40 + (c4 << 3);
  int wrB = r * 40 + (c4 << 2);

  for (int k0 = 0; k0 < K; k0 += 32) {
    float4 av = *(const float4*)(arp + k0 + (c4 << 3));  // 8 bf16 = 16B
    float4 b0 = *(const float4*)(brp + k0 + (c4 << 2));
    float4 b1 = *(const float4*)(brp + k0 + 16 + (c4 << 2));
    __syncthreads();
    *(float4*)&As[wrA] = av;
    *(uint2*)&Bs[wrB]      = make_uint2(pk2(b0.x, b0.y), pk2(b0.z, b0.w));
    *(uint2*)&Bs[wrB + 16] = make_uint2(pk2(b1.x, b1.y), pk2(b1.z, b1.w));
    __syncthreads();
    bf16x8 a0 = ldfrag(&As[a_off]);
    bf16x8 a1 = ldfrag(&As[a_off + 640]);
    bf16x8 bb0 = ldfrag(&Bs[b_off]);
    bf16x8 bb1 = ldfrag(&Bs[b_off + 640]);
    acc[0][0] = __builtin_amdgcn_mfma_f32_16x16x32_bf16(a0, bb0, acc[0][0], 0, 0, 0);
    acc[0][1] = __builtin_amdgcn_mfma_f32_16x16x32_bf16(a0, bb1, acc[0][1], 0, 0, 0);
    acc[1][0] = __builtin_amdgcn_mfma_f32_16x16x32_bf16(a1, bb0, acc[1][0], 0, 0, 0);
    acc[1][1] = __builtin_amdgcn_mfma_f32_16x16x32_bf16(a1, bb1, acc[1][1], 0, 0, 0);
  }

#pragma unroll
  for (int i = 0; i < 2; i++)
#pragma unroll
    for (int j = 0; j < 2; j++)
#pragma unroll
      for (int g = 0; g < 4; g++) {
        int ml = mq * 32 + i * 16 + quad * 4 + g;
        int row = mt * 64 + ml;
        int col = nt * 64 + nq * 32 + j * 16 + l16;
        float v = acc[i][j][g];
        if (ptok) {
          if (row < cnt) {
            int tok = ptok[(e << 9) + row];
            float w = pw[(e << 9) + row];
            atomicAdd(&out[(size_t)tok * C_DIM + col], w * v);
          }
        } else {
          out[(size_t)row * C_DIM + col] = sgate[row] * v;
        }
      }
}

extern "C" void kernel_launch(void* const* d_in, const int* in_sizes, int n_in,
                              void* d_out, int out_size, void* d_ws, size_t ws_size,
                              hipStream_t stream) {
  const float* x = (const float*)d_in[0];
  const float* gate_w = (const float*)d_in[1];
  const float* w_gate = (const float*)d_in[2];
  const float* w_up = (const float*)d_in[3];
  const float* w_down = (const float*)d_in[4];
  const float* sh_gate = (const float*)d_in[5];
  const float* sh_up = (const float*)d_in[6];
  const float* sh_down = (const float*)d_in[7];
  const float* se_gate_w = (const float*)d_in[8];
  float* out = (float*)d_out;

  char* ws = (char*)d_ws;
  int* counts = (int*)(ws + 0);                  // 32 B
  int* ptok = (int*)(ws + 1024);                 // 8*512*4 = 16 KB
  float* pw = (float*)(ws + 1024 + 16384);       // 16 KB
  float* sg = (float*)(ws + 1024 + 32768);       // 2 KB
  u16* hbuf = (u16*)(ws + 65536);                // 8*512*1024 bf16 = 8 MB
  u16* hs = (u16*)(ws + 65536 + 8388608);        // 512*2048 bf16 = 2 MB

  hipMemsetAsync(counts, 0, 32, stream);
  routing_kernel<<<512, 64, 0, stream>>>(x, gate_w, se_gate_w, counts, ptok, pw, sg);

  // expert gate+up: N=H=1024, K=C=2048, 8 m-tiles per expert
  gateup_kernel<<<dim3(16, 64), 256, 0, stream>>>(
      x, w_gate, w_up, hbuf, ptok, counts, H_DIM, C_DIM, 8, 0);
  // shared gate+up: N=HS=2048, K=C=2048, M=512
  gateup_kernel<<<dim3(32, 8), 256, 0, stream>>>(
      x, sh_gate, sh_up, hs, nullptr, nullptr, HS_DIM, C_DIM, 8, T_DIM);
  // shared down: writes out = sgate*shared  (must precede expert atomics)
  down_kernel<<<dim3(32, 8), 256, 0, stream>>>(
      hs, sh_down, out, nullptr, nullptr, sg, nullptr, C_DIM, HS_DIM, 8, T_DIM);
  // expert down: atomicAdd(out, pw * v)
  down_kernel<<<dim3(32, 64), 256, 0, stream>>>(
      hbuf, w_down, out, ptok, pw, nullptr, counts, C_DIM, H_DIM, 8, 0);
}